// Round 1
// baseline (28834.668 us; speedup 1.0000x reference)
//
#include <hip/hip_runtime.h>
#include <math.h>

#define BB   4
#define SS   2048
#define HH   1024
#define HHF  512
#define NWG  192
#define REC_WGS 128
#define NTH  256

__device__ __forceinline__ float dot4f(float4 a, float4 b){
  return a.x*b.x + a.y*b.y + a.z*b.z + a.w*b.w;
}

// ---------- transpose h-part of tau_w1: w1hT[m][i] = tau_w1[1024+i][m] ----------
__global__ __launch_bounds__(256) void transpose_w1h(const float* __restrict__ tw1,
                                                     float* __restrict__ w1hT){
  __shared__ float ts[32][33];
  int c  = threadIdx.x & 31;
  int r4 = (threadIdx.x >> 5) * 4;
  int bi = blockIdx.x * 32;   // i base (0..1023)
  int bm = blockIdx.y * 32;   // m base (0..511)
  #pragma unroll
  for (int rr = 0; rr < 4; ++rr)
    ts[r4+rr][c] = tw1[(size_t)(1024 + bi + r4 + rr) * 512 + bm + c];
  __syncthreads();
  #pragma unroll
  for (int rr = 0; rr < 4; ++rr)
    w1hT[(size_t)(bm + r4 + rr) * 1024 + bi + c] = ts[c][r4+rr];
}

// ---------- xtau[r][m] = X[r][:] @ tau_w1[:1024][m] + b1[m],  r = b*S+s ----------
__global__ __launch_bounds__(256) void gemm_xtau(const float* __restrict__ X,
                                                 const float* __restrict__ tw1,
                                                 const float* __restrict__ b1,
                                                 float* __restrict__ xtau){
  __shared__ float Xs[16][68];   // [k][row]
  __shared__ float Ws[16][68];   // [k][col]
  const int tid = threadIdx.x;
  const int tx = tid & 15, ty = tid >> 4;
  const int rowbase = blockIdx.y * 64;
  const int colbase = blockIdx.x * 64;
  const int xr  = tid >> 2,  xk4 = (tid & 3) * 4;
  const int wr  = tid >> 4,  wc4 = (tid & 15) * 4;
  float acc[4][4];
  #pragma unroll
  for (int i=0;i<4;++i){
    #pragma unroll
    for (int j=0;j<4;++j) acc[i][j]=0.f;
  }
  for (int k0 = 0; k0 < 1024; k0 += 16){
    float4 xv = *(const float4*)&X  [(size_t)(rowbase + xr)*1024 + k0 + xk4];
    float4 wv = *(const float4*)&tw1[(size_t)(k0 + wr)*512 + colbase + wc4];
    __syncthreads();
    Xs[xk4+0][xr]=xv.x; Xs[xk4+1][xr]=xv.y; Xs[xk4+2][xr]=xv.z; Xs[xk4+3][xr]=xv.w;
    *(float4*)&Ws[wr][wc4] = wv;
    __syncthreads();
    #pragma unroll
    for (int kk=0;kk<16;++kk){
      float4 av = *(const float4*)&Xs[kk][ty*4];
      float4 bv = *(const float4*)&Ws[kk][tx*4];
      acc[0][0]+=av.x*bv.x; acc[0][1]+=av.x*bv.y; acc[0][2]+=av.x*bv.z; acc[0][3]+=av.x*bv.w;
      acc[1][0]+=av.y*bv.x; acc[1][1]+=av.y*bv.y; acc[1][2]+=av.y*bv.z; acc[1][3]+=av.y*bv.w;
      acc[2][0]+=av.z*bv.x; acc[2][1]+=av.z*bv.y; acc[2][2]+=av.z*bv.z; acc[2][3]+=av.z*bv.w;
      acc[3][0]+=av.w*bv.x; acc[3][1]+=av.w*bv.y; acc[3][2]+=av.w*bv.z; acc[3][3]+=av.w*bv.w;
    }
  }
  float4 bias = *(const float4*)&b1[colbase + tx*4];
  #pragma unroll
  for (int i=0;i<4;++i){
    float4 o;
    o.x=acc[i][0]+bias.x; o.y=acc[i][1]+bias.y; o.z=acc[i][2]+bias.z; o.w=acc[i][3]+bias.w;
    *(float4*)&xtau[(size_t)(rowbase + ty*4 + i)*512 + colbase + tx*4] = o;
  }
}

// ---------- persistent liquid recurrence (one device barrier per step) ----------
__global__ __launch_bounds__(256, 1) void liquid_kernel(
    const float* __restrict__ X, const float* __restrict__ Wrec,
    const float* __restrict__ w1hT, const float* __restrict__ tw2,
    const float* __restrict__ tb2, const float* __restrict__ lng,
    const float* __restrict__ lnb, const float* __restrict__ xtau,
    float* __restrict__ fbuf, float* __restrict__ tau_slot,
    unsigned int* __restrict__ bar, float* __restrict__ out)
{
  __shared__ float hs[4][1024];
  __shared__ float red_stage[4][8];
  __shared__ float tau_stage[4];
  __shared__ float stat_lds[8];
  __shared__ float w2_lds[8];

  const int tid  = threadIdx.x;
  const int wv   = tid >> 6;      // wave == batch for h'/LN phase
  const int lane = tid & 63;
  const int wg   = blockIdx.x;

  for (int p = tid; p < 4096; p += NTH) (&hs[0][0])[p] = 0.f;

  // weight rows (8 virtual rows per WG) resident in VGPRs
  float4 wreg[2][4];
  #pragma unroll
  for (int rr = 0; rr < 2; ++rr){
    int vrow = wg*8 + wv*2 + rr;
    const float* wrow = (vrow < 1024) ? (Wrec + (size_t)vrow*1024)
                                      : (w1hT + (size_t)(vrow - 1024)*1024);
    #pragma unroll
    for (int k = 0; k < 4; ++k)
      wreg[rr][k] = *(const float4*)&wrow[4*lane + 256*k];
  }
  float4 g4[4], be4[4];
  #pragma unroll
  for (int k = 0; k < 4; ++k){
    g4[k]  = *(const float4*)&lng[4*lane + 256*k];
    be4[k] = *(const float4*)&lnb[4*lane + 256*k];
  }
  const float b2 = tb2[0];
  if (wg >= REC_WGS && tid < 8) w2_lds[tid] = tw2[(wg - REC_WGS)*8 + tid];
  __syncthreads();

  unsigned int target = 0;
  for (int t = 0; t < SS; ++t){
    // ---- prefetch the x / xtau scalars needed by the epilogue (no h dependency)
    const int ew = tid >> 3, ea = tid & 7;
    const int erow = (ea >> 2), eb = ea & 3;
    const int elrow = ew*2 + erow;
    float xpre = 0.f;
    if (tid < 32){
      if (wg < REC_WGS)
        xpre = X[((size_t)eb*SS + t)*HH + wg*8 + elrow];
      else
        xpre = xtau[((size_t)eb*SS + t)*HHF + (wg - REC_WGS)*8 + elrow];
    }
    // ---- matvec: 8 rows x 4 batches, weights in regs, h from LDS
    float acc[8];
    #pragma unroll
    for (int a=0;a<8;++a) acc[a]=0.f;
    #pragma unroll
    for (int k=0;k<4;++k){
      const int off = 4*lane + 256*k;
      float4 h0 = *(const float4*)&hs[0][off];
      float4 h1 = *(const float4*)&hs[1][off];
      float4 h2 = *(const float4*)&hs[2][off];
      float4 h3 = *(const float4*)&hs[3][off];
      #pragma unroll
      for (int rr=0;rr<2;++rr){
        acc[rr*4+0] += dot4f(wreg[rr][k], h0);
        acc[rr*4+1] += dot4f(wreg[rr][k], h1);
        acc[rr*4+2] += dot4f(wreg[rr][k], h2);
        acc[rr*4+3] += dot4f(wreg[rr][k], h3);
      }
    }
    #pragma unroll
    for (int a=0;a<8;++a){
      float v = acc[a];
      #pragma unroll
      for (int o=32;o>0;o>>=1) v += __shfl_xor(v, o, 64);
      acc[a]=v;
    }
    if (lane == 0){
      #pragma unroll
      for (int a=0;a<8;++a) red_stage[wv][a] = acc[a];
    }
    __syncthreads();
    // ---- epilogue: f writes (rec rows) / tau partial (tau rows)
    if (tid < 32){
      float val = red_stage[ew][ea];
      if (wg < REC_WGS){
        float f = tanhf(xpre + val);
        fbuf[(size_t)(t & 1)*4096 + eb*1024 + wg*8 + elrow] = f;
      } else {
        float t1 = tanhf(xpre + val);
        float contrib = t1 * w2_lds[elrow];
        contrib += __shfl_xor(contrib, 4, 64);
        contrib += __shfl_xor(contrib, 8, 64);
        contrib += __shfl_xor(contrib, 16, 64);
        if (tid < 4) atomicAdd(&tau_slot[(t % 3)*4 + tid], contrib);
      }
    }
    __syncthreads();   // drains all vmem (compiler emits vmcnt(0) before s_barrier)
    // ---- device barrier: 4 striped monotonic counters
    if (tid == 0)
      __hip_atomic_fetch_add(&bar[(wg & 3)*16], 1u, __ATOMIC_RELEASE, __HIP_MEMORY_SCOPE_AGENT);
    target += NWG;
    if (tid == 0){
      int guard = 0;
      while (guard < 200000000){
        unsigned int s = __hip_atomic_load(&bar[0],  __ATOMIC_RELAXED, __HIP_MEMORY_SCOPE_AGENT)
                       + __hip_atomic_load(&bar[16], __ATOMIC_RELAXED, __HIP_MEMORY_SCOPE_AGENT)
                       + __hip_atomic_load(&bar[32], __ATOMIC_RELAXED, __HIP_MEMORY_SCOPE_AGENT)
                       + __hip_atomic_load(&bar[48], __ATOMIC_RELAXED, __HIP_MEMORY_SCOPE_AGENT);
        if (s >= target) break;
        __builtin_amdgcn_s_sleep(2);
        ++guard;
      }
    }
    __syncthreads();
    __builtin_amdgcn_fence(__ATOMIC_ACQUIRE, "agent");

    // ---- post-barrier: reconstruct h' redundantly, LN, next h
    float4 f4[4];
    const float* fb = fbuf + (size_t)(t & 1)*4096 + wv*1024;
    #pragma unroll
    for (int k=0;k<4;++k) f4[k] = *(const float4*)&fb[4*lane + 256*k];
    if (tid < 4)
      tau_stage[tid] = __hip_atomic_load(&tau_slot[(t % 3)*4 + tid],
                                         __ATOMIC_RELAXED, __HIP_MEMORY_SCOPE_AGENT);
    if (wg == 0 && tid >= 32 && tid < 36)
      __hip_atomic_store(&tau_slot[((t + 2) % 3)*4 + (tid - 32)], 0.f,
                         __ATOMIC_RELAXED, __HIP_MEMORY_SCOPE_AGENT);
    __syncthreads();
    float pre = tau_stage[wv] + b2;
    float sig = 1.f / (1.f + expf(-pre));
    float tau = 1.f + 4.f * sig;
    float al  = 0.1f / tau;
    float s1 = 0.f, s2 = 0.f;
    float4 hp4[4];
    #pragma unroll
    for (int k=0;k<4;++k){
      const int off = 4*lane + 256*k;
      float4 h4 = *(const float4*)&hs[wv][off];
      float4 hp;
      hp.x = h4.x + al*(f4[k].x - h4.x);
      hp.y = h4.y + al*(f4[k].y - h4.y);
      hp.z = h4.z + al*(f4[k].z - h4.z);
      hp.w = h4.w + al*(f4[k].w - h4.w);
      hp4[k] = hp;
      s1 += hp.x + hp.y + hp.z + hp.w;
      s2 += hp.x*hp.x + hp.y*hp.y + hp.z*hp.z + hp.w*hp.w;
    }
    #pragma unroll
    for (int o=32;o>0;o>>=1){
      s1 += __shfl_xor(s1, o, 64);
      s2 += __shfl_xor(s2, o, 64);
    }
    if (lane == 0){ stat_lds[wv*2] = s1; stat_lds[wv*2+1] = s2; }
    __syncthreads();
    float mu   = stat_lds[wv*2]   * (1.f/1024.f);
    float var  = stat_lds[wv*2+1] * (1.f/1024.f) - mu*mu;
    float rstd = rsqrtf(var + 1e-5f);
    #pragma unroll
    for (int k=0;k<4;++k){
      const int off = 4*lane + 256*k;
      float4 hp = hp4[k];
      float4 o4;
      o4.x = (hp.x - mu)*rstd*g4[k].x + be4[k].x;
      o4.y = (hp.y - mu)*rstd*g4[k].y + be4[k].y;
      o4.z = (hp.z - mu)*rstd*g4[k].z + be4[k].z;
      o4.w = (hp.w - mu)*rstd*g4[k].w + be4[k].w;
      *(float4*)&hs[wv][off] = o4;
    }
    __syncthreads();
    if (wg < 16){
      int idx = wg*NTH + tid;
      int ob = idx >> 10, oi = idx & 1023;
      out[((size_t)ob*SS + t)*HH + oi] = hs[ob][oi];
    }
  }
}

// ---------- out = sc + 0.01*(liq - sc), in place over liq ----------
__global__ __launch_bounds__(256) void finalize_kernel(const float* __restrict__ X,
                                                       const float* __restrict__ cw,
                                                       float* __restrict__ out){
  size_t gid = (size_t)blockIdx.x * 256 + threadIdx.x;
  size_t gi  = gid * 4;
  int b   = (int)(gi >> 21);
  int rem = (int)(gi & 2097151);
  int t   = rem >> 10;
  int i   = rem & 1023;
  float4 l4 = *(const float4*)&out[gi];
  const float* xb = X + ((size_t)b*SS)*HH + i;
  float4 z4 = make_float4(0.f,0.f,0.f,0.f);
  float4 xk0 = (t >= 3) ? *(const float4*)&xb[(size_t)(t-3)*HH] : z4;
  float4 xk1 = (t >= 2) ? *(const float4*)&xb[(size_t)(t-2)*HH] : z4;
  float4 xk2 = (t >= 1) ? *(const float4*)&xb[(size_t)(t-1)*HH] : z4;
  float4 xk3 =            *(const float4*)&xb[(size_t)t*HH];
  float4 cw0 = *(const float4*)&cw[(i+0)*4];
  float4 cw1 = *(const float4*)&cw[(i+1)*4];
  float4 cw2 = *(const float4*)&cw[(i+2)*4];
  float4 cw3 = *(const float4*)&cw[(i+3)*4];
  float4 sc;
  sc.x = cw0.x*xk0.x + cw0.y*xk1.x + cw0.z*xk2.x + cw0.w*xk3.x;
  sc.y = cw1.x*xk0.y + cw1.y*xk1.y + cw1.z*xk2.y + cw1.w*xk3.y;
  sc.z = cw2.x*xk0.z + cw2.y*xk1.z + cw2.z*xk2.z + cw2.w*xk3.z;
  sc.w = cw3.x*xk0.w + cw3.y*xk1.w + cw3.z*xk2.w + cw3.w*xk3.w;
  float4 o;
  o.x = sc.x + 0.01f*(l4.x - sc.x);
  o.y = sc.y + 0.01f*(l4.y - sc.y);
  o.z = sc.z + 0.01f*(l4.z - sc.z);
  o.w = sc.w + 0.01f*(l4.w - sc.w);
  *(float4*)&out[gi] = o;
}

extern "C" void kernel_launch(void* const* d_in, const int* in_sizes, int n_in,
                              void* d_out, int out_size, void* d_ws, size_t ws_size,
                              hipStream_t stream) {
  const float* X     = (const float*)d_in[0];
  const float* convw = (const float*)d_in[1];
  const float* Wrec  = (const float*)d_in[2];
  const float* tw1   = (const float*)d_in[3];
  const float* tb1   = (const float*)d_in[4];
  const float* tw2   = (const float*)d_in[5];
  const float* tb2   = (const float*)d_in[6];
  const float* lng   = (const float*)d_in[7];
  const float* lnb   = (const float*)d_in[8];
  float* out = (float*)d_out;
  float* wsf = (float*)d_ws;

  unsigned int* bar = (unsigned int*)d_ws;        // 4 counters at byte 0,64,128,192
  float* tau_slot = wsf + 64;                     // 3 slots x 4 batches
  float* fbuf     = wsf + 128;                    // 2 x 4 x 1024
  float* w1hT     = wsf + 8448;                   // 512 x 1024
  float* xtau     = w1hT + 512*1024;              // 8192 x 512

  hipMemsetAsync(d_ws, 0, 512, stream);
  transpose_w1h<<<dim3(32,16), dim3(256), 0, stream>>>(tw1, w1hT);
  gemm_xtau   <<<dim3(8,128),  dim3(256), 0, stream>>>(X, tw1, tb1, xtau);
  liquid_kernel<<<dim3(NWG),   dim3(NTH), 0, stream>>>(X, Wrec, w1hT, tw2, tb2,
                                                       lng, lnb, xtau, fbuf,
                                                       tau_slot, bar, out);
  finalize_kernel<<<dim3(8192), dim3(256), 0, stream>>>(X, convw, out);
}

// Round 2
// 9829.314 us; speedup vs baseline: 2.9335x; 2.9335x over previous
//
#include <hip/hip_runtime.h>
#include <math.h>

#define BB   4
#define SS   2048
#define HH   1024
#define HHF  512
#define NWG  192
#define REC_WGS 128
#define NTH  256

__device__ __forceinline__ float dot4f(float4 a, float4 b){
  return a.x*b.x + a.y*b.y + a.z*b.z + a.w*b.w;
}

// 8-byte coherent (L2-bypassing) load/store helpers: relaxed agent-scope atomics -> sc1
__device__ __forceinline__ float2 aload2(const float* p){
  unsigned long long v = __hip_atomic_load((const unsigned long long*)p,
                                           __ATOMIC_RELAXED, __HIP_MEMORY_SCOPE_AGENT);
  union { unsigned long long u; float2 f; } c; c.u = v; return c.f;
}
__device__ __forceinline__ void astore1(float* p, float v){
  __hip_atomic_store(p, v, __ATOMIC_RELAXED, __HIP_MEMORY_SCOPE_AGENT);
}
__device__ __forceinline__ float aload1(const float* p){
  return __hip_atomic_load(p, __ATOMIC_RELAXED, __HIP_MEMORY_SCOPE_AGENT);
}

// ---------- transpose h-part of tau_w1: w1hT[m][i] = tau_w1[1024+i][m] ----------
__global__ __launch_bounds__(256) void transpose_w1h(const float* __restrict__ tw1,
                                                     float* __restrict__ w1hT){
  __shared__ float ts[32][33];
  int c  = threadIdx.x & 31;
  int r4 = (threadIdx.x >> 5) * 4;
  int bi = blockIdx.x * 32;   // i base (0..1023)
  int bm = blockIdx.y * 32;   // m base (0..511)
  #pragma unroll
  for (int rr = 0; rr < 4; ++rr)
    ts[r4+rr][c] = tw1[(size_t)(1024 + bi + r4 + rr) * 512 + bm + c];
  __syncthreads();
  #pragma unroll
  for (int rr = 0; rr < 4; ++rr)
    w1hT[(size_t)(bm + r4 + rr) * 1024 + bi + c] = ts[c][r4+rr];
}

// ---------- xtau[r][m] = X[r][:] @ tau_w1[:1024][m] + b1[m],  r = b*S+s ----------
__global__ __launch_bounds__(256) void gemm_xtau(const float* __restrict__ X,
                                                 const float* __restrict__ tw1,
                                                 const float* __restrict__ b1,
                                                 float* __restrict__ xtau){
  __shared__ float Xs[16][68];   // [k][row]
  __shared__ float Ws[16][68];   // [k][col]
  const int tid = threadIdx.x;
  const int tx = tid & 15, ty = tid >> 4;
  const int rowbase = blockIdx.y * 64;
  const int colbase = blockIdx.x * 64;
  const int xr  = tid >> 2,  xk4 = (tid & 3) * 4;
  const int wr  = tid >> 4,  wc4 = (tid & 15) * 4;
  float acc[4][4];
  #pragma unroll
  for (int i=0;i<4;++i){
    #pragma unroll
    for (int j=0;j<4;++j) acc[i][j]=0.f;
  }
  for (int k0 = 0; k0 < 1024; k0 += 16){
    float4 xv = *(const float4*)&X  [(size_t)(rowbase + xr)*1024 + k0 + xk4];
    float4 wv = *(const float4*)&tw1[(size_t)(k0 + wr)*512 + colbase + wc4];
    __syncthreads();
    Xs[xk4+0][xr]=xv.x; Xs[xk4+1][xr]=xv.y; Xs[xk4+2][xr]=xv.z; Xs[xk4+3][xr]=xv.w;
    *(float4*)&Ws[wr][wc4] = wv;
    __syncthreads();
    #pragma unroll
    for (int kk=0;kk<16;++kk){
      float4 av = *(const float4*)&Xs[kk][ty*4];
      float4 bv = *(const float4*)&Ws[kk][tx*4];
      acc[0][0]+=av.x*bv.x; acc[0][1]+=av.x*bv.y; acc[0][2]+=av.x*bv.z; acc[0][3]+=av.x*bv.w;
      acc[1][0]+=av.y*bv.x; acc[1][1]+=av.y*bv.y; acc[1][2]+=av.y*bv.z; acc[1][3]+=av.y*bv.w;
      acc[2][0]+=av.z*bv.x; acc[2][1]+=av.z*bv.y; acc[2][2]+=av.z*bv.z; acc[2][3]+=av.z*bv.w;
      acc[3][0]+=av.w*bv.x; acc[3][1]+=av.w*bv.y; acc[3][2]+=av.w*bv.z; acc[3][3]+=av.w*bv.w;
    }
  }
  float4 bias = *(const float4*)&b1[colbase + tx*4];
  #pragma unroll
  for (int i=0;i<4;++i){
    float4 o;
    o.x=acc[i][0]+bias.x; o.y=acc[i][1]+bias.y; o.z=acc[i][2]+bias.z; o.w=acc[i][3]+bias.w;
    *(float4*)&xtau[(size_t)(rowbase + ty*4 + i)*512 + colbase + tx*4] = o;
  }
}

// ---------- persistent liquid recurrence (one device barrier per step) ----------
// All cross-WG traffic (fbuf, tau_slot, bar) goes through relaxed AGENT-scope
// atomics (sc1, L2-bypass) -> no buffer_wbl2/buffer_inv fences anywhere.
__global__ __launch_bounds__(256, 1) void liquid_kernel(
    const float* __restrict__ X, const float* __restrict__ Wrec,
    const float* __restrict__ w1hT, const float* __restrict__ tw2,
    const float* __restrict__ tb2, const float* __restrict__ lng,
    const float* __restrict__ lnb, const float* __restrict__ xtau,
    float* __restrict__ fbuf, float* __restrict__ tau_slot,
    unsigned int* __restrict__ bar, float* __restrict__ out)
{
  __shared__ float hs[4][1024];
  __shared__ float red_stage[4][8];
  __shared__ float tau_stage[4];
  __shared__ float stat_lds[8];
  __shared__ float w2_lds[8];

  const int tid  = threadIdx.x;
  const int wv   = tid >> 6;      // wave == batch for h'/LN phase
  const int lane = tid & 63;
  const int wg   = blockIdx.x;

  for (int p = tid; p < 4096; p += NTH) (&hs[0][0])[p] = 0.f;

  // weight rows (8 virtual rows per WG) resident in VGPRs
  float4 wreg[2][4];
  #pragma unroll
  for (int rr = 0; rr < 2; ++rr){
    int vrow = wg*8 + wv*2 + rr;
    const float* wrow = (vrow < 1024) ? (Wrec + (size_t)vrow*1024)
                                      : (w1hT + (size_t)(vrow - 1024)*1024);
    #pragma unroll
    for (int k = 0; k < 4; ++k)
      wreg[rr][k] = *(const float4*)&wrow[4*lane + 256*k];
  }
  float4 g4[4], be4[4];
  #pragma unroll
  for (int k = 0; k < 4; ++k){
    g4[k]  = *(const float4*)&lng[4*lane + 256*k];
    be4[k] = *(const float4*)&lnb[4*lane + 256*k];
  }
  const float b2 = tb2[0];
  if (wg >= REC_WGS && tid < 8) w2_lds[tid] = tw2[(wg - REC_WGS)*8 + tid];
  __syncthreads();

  unsigned int target = 0;
  for (int t = 0; t < SS; ++t){
    // ---- prefetch the x / xtau scalars needed by the epilogue (no h dependency)
    const int ew = tid >> 3, ea = tid & 7;
    const int erow = (ea >> 2), eb = ea & 3;
    const int elrow = ew*2 + erow;
    float xpre = 0.f;
    if (tid < 32){
      if (wg < REC_WGS)
        xpre = X[((size_t)eb*SS + t)*HH + wg*8 + elrow];
      else
        xpre = xtau[((size_t)eb*SS + t)*HHF + (wg - REC_WGS)*8 + elrow];
    }
    // ---- matvec: 8 rows x 4 batches, weights in regs, h from LDS
    float acc[8];
    #pragma unroll
    for (int a=0;a<8;++a) acc[a]=0.f;
    #pragma unroll
    for (int k=0;k<4;++k){
      const int off = 4*lane + 256*k;
      float4 h0 = *(const float4*)&hs[0][off];
      float4 h1 = *(const float4*)&hs[1][off];
      float4 h2 = *(const float4*)&hs[2][off];
      float4 h3 = *(const float4*)&hs[3][off];
      #pragma unroll
      for (int rr=0;rr<2;++rr){
        acc[rr*4+0] += dot4f(wreg[rr][k], h0);
        acc[rr*4+1] += dot4f(wreg[rr][k], h1);
        acc[rr*4+2] += dot4f(wreg[rr][k], h2);
        acc[rr*4+3] += dot4f(wreg[rr][k], h3);
      }
    }
    #pragma unroll
    for (int a=0;a<8;++a){
      float v = acc[a];
      #pragma unroll
      for (int o=32;o>0;o>>=1) v += __shfl_xor(v, o, 64);
      acc[a]=v;
    }
    if (lane == 0){
      #pragma unroll
      for (int a=0;a<8;++a) red_stage[wv][a] = acc[a];
    }
    __syncthreads();
    // ---- epilogue: f writes (rec rows) / tau partial (tau rows) -- all sc1 atomics
    if (tid < 32){
      float val = red_stage[ew][ea];
      if (wg < REC_WGS){
        float f = tanhf(xpre + val);
        astore1(&fbuf[(size_t)(t & 1)*4096 + eb*1024 + wg*8 + elrow], f);
      } else {
        float t1 = tanhf(xpre + val);
        float contrib = t1 * w2_lds[elrow];
        contrib += __shfl_xor(contrib, 4, 64);
        contrib += __shfl_xor(contrib, 8, 64);
        contrib += __shfl_xor(contrib, 16, 64);
        if (tid < 4)
          __hip_atomic_fetch_add(&tau_slot[(t % 3)*4 + tid], contrib,
                                 __ATOMIC_RELAXED, __HIP_MEMORY_SCOPE_AGENT);
      }
    }
    __syncthreads();   // emits s_waitcnt vmcnt(0): sc1 stores are at the coherent point
    asm volatile("" ::: "memory");
    // ---- device barrier: 4 striped monotonic counters, relaxed agent atomics only
    if (tid == 0)
      __hip_atomic_fetch_add(&bar[(wg & 3)*16], 1u, __ATOMIC_RELAXED, __HIP_MEMORY_SCOPE_AGENT);
    target += NWG;
    if (tid == 0){
      int guard = 0;
      while (guard < 200000000){
        unsigned int s = __hip_atomic_load(&bar[0],  __ATOMIC_RELAXED, __HIP_MEMORY_SCOPE_AGENT)
                       + __hip_atomic_load(&bar[16], __ATOMIC_RELAXED, __HIP_MEMORY_SCOPE_AGENT)
                       + __hip_atomic_load(&bar[32], __ATOMIC_RELAXED, __HIP_MEMORY_SCOPE_AGENT)
                       + __hip_atomic_load(&bar[48], __ATOMIC_RELAXED, __HIP_MEMORY_SCOPE_AGENT);
        if (s >= target) break;
        __builtin_amdgcn_s_sleep(1);
        ++guard;
      }
    }
    asm volatile("" ::: "memory");
    __syncthreads();

    // ---- post-barrier: reconstruct h' redundantly, LN, next h
    float4 f4[4];
    const float* fb = fbuf + (size_t)(t & 1)*4096 + wv*1024;
    #pragma unroll
    for (int k=0;k<4;++k){
      float2 lo = aload2(&fb[4*lane + 256*k]);
      float2 hi = aload2(&fb[4*lane + 256*k + 2]);
      f4[k].x = lo.x; f4[k].y = lo.y; f4[k].z = hi.x; f4[k].w = hi.y;
    }
    if (tid < 4)
      tau_stage[tid] = aload1(&tau_slot[(t % 3)*4 + tid]);
    if (wg == 0 && tid >= 32 && tid < 36)
      astore1(&tau_slot[((t + 2) % 3)*4 + (tid - 32)], 0.f);
    __syncthreads();
    float pre = tau_stage[wv] + b2;
    float sig = 1.f / (1.f + expf(-pre));
    float tau = 1.f + 4.f * sig;
    float al  = 0.1f / tau;
    float s1 = 0.f, s2 = 0.f;
    float4 hp4[4];
    #pragma unroll
    for (int k=0;k<4;++k){
      const int off = 4*lane + 256*k;
      float4 h4 = *(const float4*)&hs[wv][off];
      float4 hp;
      hp.x = h4.x + al*(f4[k].x - h4.x);
      hp.y = h4.y + al*(f4[k].y - h4.y);
      hp.z = h4.z + al*(f4[k].z - h4.z);
      hp.w = h4.w + al*(f4[k].w - h4.w);
      hp4[k] = hp;
      s1 += hp.x + hp.y + hp.z + hp.w;
      s2 += hp.x*hp.x + hp.y*hp.y + hp.z*hp.z + hp.w*hp.w;
    }
    #pragma unroll
    for (int o=32;o>0;o>>=1){
      s1 += __shfl_xor(s1, o, 64);
      s2 += __shfl_xor(s2, o, 64);
    }
    if (lane == 0){ stat_lds[wv*2] = s1; stat_lds[wv*2+1] = s2; }
    __syncthreads();
    float mu   = stat_lds[wv*2]   * (1.f/1024.f);
    float var  = stat_lds[wv*2+1] * (1.f/1024.f) - mu*mu;
    float rstd = rsqrtf(var + 1e-5f);
    #pragma unroll
    for (int k=0;k<4;++k){
      const int off = 4*lane + 256*k;
      float4 hp = hp4[k];
      float4 o4;
      o4.x = (hp.x - mu)*rstd*g4[k].x + be4[k].x;
      o4.y = (hp.y - mu)*rstd*g4[k].y + be4[k].y;
      o4.z = (hp.z - mu)*rstd*g4[k].z + be4[k].z;
      o4.w = (hp.w - mu)*rstd*g4[k].w + be4[k].w;
      *(float4*)&hs[wv][off] = o4;
    }
    __syncthreads();
    if (wg < 16){
      int idx = wg*NTH + tid;
      int ob = idx >> 10, oi = idx & 1023;
      out[((size_t)ob*SS + t)*HH + oi] = hs[ob][oi];
    }
  }
}

// ---------- out = sc + 0.01*(liq - sc), in place over liq ----------
__global__ __launch_bounds__(256) void finalize_kernel(const float* __restrict__ X,
                                                       const float* __restrict__ cw,
                                                       float* __restrict__ out){
  size_t gid = (size_t)blockIdx.x * 256 + threadIdx.x;
  size_t gi  = gid * 4;
  int b   = (int)(gi >> 21);
  int rem = (int)(gi & 2097151);
  int t   = rem >> 10;
  int i   = rem & 1023;
  float4 l4 = *(const float4*)&out[gi];
  const float* xb = X + ((size_t)b*SS)*HH + i;
  float4 z4 = make_float4(0.f,0.f,0.f,0.f);
  float4 xk0 = (t >= 3) ? *(const float4*)&xb[(size_t)(t-3)*HH] : z4;
  float4 xk1 = (t >= 2) ? *(const float4*)&xb[(size_t)(t-2)*HH] : z4;
  float4 xk2 = (t >= 1) ? *(const float4*)&xb[(size_t)(t-1)*HH] : z4;
  float4 xk3 =            *(const float4*)&xb[(size_t)t*HH];
  float4 cw0 = *(const float4*)&cw[(i+0)*4];
  float4 cw1 = *(const float4*)&cw[(i+1)*4];
  float4 cw2 = *(const float4*)&cw[(i+2)*4];
  float4 cw3 = *(const float4*)&cw[(i+3)*4];
  float4 sc;
  sc.x = cw0.x*xk0.x + cw0.y*xk1.x + cw0.z*xk2.x + cw0.w*xk3.x;
  sc.y = cw1.x*xk0.y + cw1.y*xk1.y + cw1.z*xk2.y + cw1.w*xk3.y;
  sc.z = cw2.x*xk0.z + cw2.y*xk1.z + cw2.z*xk2.z + cw2.w*xk3.z;
  sc.w = cw3.x*xk0.w + cw3.y*xk1.w + cw3.z*xk2.w + cw3.w*xk3.w;
  float4 o;
  o.x = sc.x + 0.01f*(l4.x - sc.x);
  o.y = sc.y + 0.01f*(l4.y - sc.y);
  o.z = sc.z + 0.01f*(l4.z - sc.z);
  o.w = sc.w + 0.01f*(l4.w - sc.w);
  *(float4*)&out[gi] = o;
}

extern "C" void kernel_launch(void* const* d_in, const int* in_sizes, int n_in,
                              void* d_out, int out_size, void* d_ws, size_t ws_size,
                              hipStream_t stream) {
  const float* X     = (const float*)d_in[0];
  const float* convw = (const float*)d_in[1];
  const float* Wrec  = (const float*)d_in[2];
  const float* tw1   = (const float*)d_in[3];
  const float* tb1   = (const float*)d_in[4];
  const float* tw2   = (const float*)d_in[5];
  const float* tb2   = (const float*)d_in[6];
  const float* lng   = (const float*)d_in[7];
  const float* lnb   = (const float*)d_in[8];
  float* out = (float*)d_out;
  float* wsf = (float*)d_ws;

  unsigned int* bar = (unsigned int*)d_ws;        // 4 counters at byte 0,64,128,192
  float* tau_slot = wsf + 64;                     // 3 slots x 4 batches
  float* fbuf     = wsf + 128;                    // 2 x 4 x 1024
  float* w1hT     = wsf + 8448;                   // 512 x 1024
  float* xtau     = w1hT + 512*1024;              // 8192 x 512

  hipMemsetAsync(d_ws, 0, 512, stream);
  transpose_w1h<<<dim3(32,16), dim3(256), 0, stream>>>(tw1, w1hT);
  gemm_xtau   <<<dim3(8,128),  dim3(256), 0, stream>>>(X, tw1, tb1, xtau);
  liquid_kernel<<<dim3(NWG),   dim3(NTH), 0, stream>>>(X, Wrec, w1hT, tw2, tb2,
                                                       lng, lnb, xtau, fbuf,
                                                       tau_slot, bar, out);
  finalize_kernel<<<dim3(8192), dim3(256), 0, stream>>>(X, convw, out);
}